// Round 1
// baseline (185.437 us; speedup 1.0000x reference)
//
#include <hip/hip_runtime.h>

// B=2, S=32, C=256, L=640, H=5, D=128
// rows M = B*S*C = 16384, L = 640 = H*D
//
// ws layout (bytes):
//   XB  @ 0          : x as bf16 [16384][640]         (20,971,520)  -- reused as attn_out after gemm1
//   QB  @ 1*SZ       : q bf16 [16384][640] (col = h*128+d)
//   KB  @ 2*SZ       : k bf16 [16384][640]
//   VTB @ 3*SZ       : v transposed bf16 [320 bsh][128 d][256 e]
//   WQB/WKB/WVB/WPB/BPB @ 4*SZ : weights bf16
//   FLAG            : u32 (1 = inputs are fp32, 0 = inputs are bf16)
// total need ~87.2 MB

typedef unsigned short u16;
typedef __bf16 bf16x8 __attribute__((ext_vector_type(8)));
typedef float f32x4 __attribute__((ext_vector_type(4)));

__device__ __forceinline__ u16 f2bf(float f){
  union { float f; unsigned u; } v; v.f = f;
  unsigned r = v.u + 0x7fffu + ((v.u >> 16) & 1u);
  return (u16)(r >> 16);
}
__device__ __forceinline__ float bf2f(u16 u){
  union { unsigned u; float f; } v; v.u = ((unsigned)u) << 16;
  return v.f;
}

// ---- swizzled LDS byte offsets (XOR 16B-chunk swizzle; write and read share these) ----
// gemm tiles: [128 rows][32 k], row = 64B (4 chunks)
__device__ __forceinline__ int g_off (int r, int k){ return r*64  + (((k>>3) ^ ((r>>1)&3)))*16 + (k&7)*2; }
// k_lds: [256 e][128 d], row = 256B (16 chunks)
__device__ __forceinline__ int k_off (int e, int d){ return e*256 + (((d>>3) ^ (e&7)))*16 + (d&7)*2; }
// vt_lds: [128 d][256 e], row = 512B (32 chunks, xor low 3 bits)
__device__ __forceinline__ int vt_off(int d, int e){ return d*512 + (((e>>3) ^ (d&7)))*16 + (e&7)*2; }
// p tile (per wave): [16 c][128 e], row = 256B (16 chunks, xor 2 bits)
__device__ __forceinline__ int p_off (int c, int el){ return c*256 + (((el>>3) ^ ((c>>2)&3)))*16 + (el&7)*2; }

// ------------------------------------------------------------------
// dtype sniffer: if buffer is fp32, the LOW u16 of each word is ~uniform
// random -> bf16-exponent >= 143 (|v|>=2^16) about 44% of the time.
// Genuine bf16 N(0,1)-scale data: never.
__global__ void k_detect(const u16* __restrict__ x, unsigned* __restrict__ flag){
  int lane = threadIdx.x & 63;
  int cnt = 0;
  for (int i = lane; i < 1024; i += 64){
    unsigned e = (x[2*i] >> 7) & 0xffu;
    cnt += (e >= 143u) ? 1 : 0;
  }
  #pragma unroll
  for (int msk = 1; msk < 64; msk <<= 1) cnt += __shfl_xor(cnt, msk);
  if (threadIdx.x == 0) *flag = (cnt > 16) ? 1u : 0u;
}

__global__ void k_convert(const void* __restrict__ src, u16* __restrict__ dst, int n4,
                          const unsigned* __restrict__ flag){
  int i = blockIdx.x * blockDim.x + threadIdx.x;
  if (i >= n4) return;
  if (*flag){
    float4 v = ((const float4*)src)[i];
    ushort4 o;
    o.x = f2bf(v.x); o.y = f2bf(v.y); o.z = f2bf(v.z); o.w = f2bf(v.w);
    ((ushort4*)dst)[i] = o;
  } else {
    ((ushort4*)dst)[i] = ((const ushort4*)src)[i];
  }
}

// ------------------------------------------------------------------
// 128x128 tile GEMM core, K=640, A[ld 640] row-major, B given as [N][K]
// (B^T form). 256 threads = 4 waves (2x2), each wave computes 64x64 = 4x4
// frags of mfma_f32_16x16x32_bf16. Reg-staged LDS with XOR swizzle.
__device__ __forceinline__ void gemm_core(const u16* __restrict__ Ag, const u16* __restrict__ Bg,
                                          char* a_lds, char* b_lds, f32x4 acc[4][4]){
  const int tid = threadIdx.x;
  const int lane = tid & 63, wid = tid >> 6;
  const int g = lane >> 4, lo = lane & 15;
  const int wm = wid >> 1, wn = wid & 1;
  const f32x4 vzero = {0.f, 0.f, 0.f, 0.f};
  #pragma unroll
  for (int mt = 0; mt < 4; ++mt)
    #pragma unroll
    for (int nt = 0; nt < 4; ++nt) acc[mt][nt] = vzero;

  for (int kt = 0; kt < 20; ++kt){
    __syncthreads();                       // previous tile fully consumed
    #pragma unroll
    for (int i = 0; i < 2; ++i){
      int slot = i*256 + tid;
      int r = slot >> 2, cd = slot & 3;    // row, data-chunk (8 bf16)
      uint4 va = *(const uint4*)(Ag + (size_t)r*640 + kt*32 + cd*8);
      uint4 vb = *(const uint4*)(Bg + (size_t)r*640 + kt*32 + cd*8);
      *(uint4*)(a_lds + g_off(r, cd*8)) = va;
      *(uint4*)(b_lds + g_off(r, cd*8)) = vb;
    }
    __syncthreads();
    bf16x8 af[4], bfr[4];
    #pragma unroll
    for (int mt = 0; mt < 4; ++mt){
      int rr = wm*64 + mt*16 + lo;
      af[mt] = *(const bf16x8*)(a_lds + g_off(rr, g*8));
    }
    #pragma unroll
    for (int nt = 0; nt < 4; ++nt){
      int rr = wn*64 + nt*16 + lo;
      bfr[nt] = *(const bf16x8*)(b_lds + g_off(rr, g*8));
    }
    #pragma unroll
    for (int mt = 0; mt < 4; ++mt)
      #pragma unroll
      for (int nt = 0; nt < 4; ++nt)
        acc[mt][nt] = __builtin_amdgcn_mfma_f32_16x16x32_bf16(af[mt], bfr[nt], acc[mt][nt], 0, 0, 0);
  }
}

// QKV projection: grid (128 mtiles, 15), by -> proj p = by/5, head h = by%5.
// v is written TRANSPOSED per (bs,h): vtb[bsh][d][e]  (free transpose in the
// scalar epilogue; lets attention read PV B-fragments as contiguous b128).
__global__ __launch_bounds__(256, 2) void gemm_qkv(const u16* __restrict__ xb,
    const u16* __restrict__ wq, const u16* __restrict__ wk, const u16* __restrict__ wv,
    u16* __restrict__ qb, u16* __restrict__ kb, u16* __restrict__ vtb){
  __shared__ char smem[16384];
  const int m0 = blockIdx.x * 128;
  const int by = blockIdx.y;
  const int p = by / 5, h = by % 5;
  const u16* W = (p == 0) ? wq : (p == 1) ? wk : wv;
  f32x4 acc[4][4];
  gemm_core(xb + (size_t)m0*640, W + (size_t)h*128*640, smem, smem + 8192, acc);
  const int tid = threadIdx.x, lane = tid & 63, wid = tid >> 6;
  const int g = lane >> 4, lo = lane & 15;
  const int wm = wid >> 1, wn = wid & 1;
  #pragma unroll
  for (int mt = 0; mt < 4; ++mt)
    #pragma unroll
    for (int nt = 0; nt < 4; ++nt)
      #pragma unroll
      for (int r = 0; r < 4; ++r){
        int m  = m0 + wm*64 + mt*16 + g*4 + r;       // global row (b,s,c)
        int nn = wn*64 + nt*16 + lo;                 // d within head, 0..127
        u16 val = f2bf(acc[mt][nt][r]);
        if (p == 0)      qb[(size_t)m*640 + h*128 + nn] = val;
        else if (p == 1) kb[(size_t)m*640 + h*128 + nn] = val;
        else             vtb[((size_t)(m >> 8)*5 + h)*32768 + (size_t)nn*256 + (m & 255)] = val;
      }
}

// Output projection + bias; writes d_out as f32 or bf16 per detected flag.
__global__ __launch_bounds__(256, 2) void gemm_out(const u16* __restrict__ at,
    const u16* __restrict__ wpw, const u16* __restrict__ bpw,
    void* __restrict__ out, const unsigned* __restrict__ flag){
  __shared__ char smem[16384];
  const int m0 = blockIdx.x * 128;
  const int n0 = blockIdx.y * 128;
  f32x4 acc[4][4];
  gemm_core(at + (size_t)m0*640, wpw + (size_t)n0*640, smem, smem + 8192, acc);
  const int tid = threadIdx.x, lane = tid & 63, wid = tid >> 6;
  const int g = lane >> 4, lo = lane & 15;
  const int wm = wid >> 1, wn = wid & 1;
  const bool f32out = (*flag != 0u);
  #pragma unroll
  for (int mt = 0; mt < 4; ++mt)
    #pragma unroll
    for (int nt = 0; nt < 4; ++nt){
      int col = n0 + wn*64 + nt*16 + lo;
      float bv = bf2f(bpw[col]);
      #pragma unroll
      for (int r = 0; r < 4; ++r){
        int m = m0 + wm*64 + mt*16 + g*4 + r;
        float v = acc[mt][nt][r] + bv;
        if (f32out) ((float*)out)[(size_t)m*640 + col] = v;
        else        ((u16*)out)[(size_t)m*640 + col]   = f2bf(v);
      }
    }
}

// ------------------------------------------------------------------
// Attention: grid = 320 (b,s,h) x 2 c-halves = 640 blocks, 256 threads.
// Stage k [256][128] and vT [128][256] in LDS (swizzled). Each wave handles
// 32 q-rows in 2 passes of one 16-row m-tile: QK^T (MFMA) -> in-register
// wave-parallel softmax -> P via small per-wave LDS tile -> PV (MFMA).
__global__ __launch_bounds__(256, 1) void attn_fwd(const u16* __restrict__ qb,
    const u16* __restrict__ kb, const u16* __restrict__ vtb, u16* __restrict__ ob){
  __shared__ char smem[147456];
  char* k_lds  = smem;               // 64 KiB
  char* vt_lds = smem + 65536;       // 64 KiB
  char* p_lds  = smem + 131072;      // 16 KiB = 4 waves x [16 c][128 e]
  const int tid = threadIdx.x;
  const int bsh = blockIdx.x >> 1;
  const int chalf = (blockIdx.x & 1) * 128;
  const int bs = bsh / 5, h = bsh % 5;
  const u16* kbase = kb + (size_t)bs*256*640 + (size_t)h*128;
  const u16* vbase = vtb + (size_t)bsh*32768;
  #pragma unroll 4
  for (int i = 0; i < 16; ++i){
    int idx = i*256 + tid;
    int e = idx >> 4, cd = idx & 15;
    uint4 kv = *(const uint4*)(kbase + (size_t)e*640 + cd*8);
    *(uint4*)(k_lds + e*256 + ((cd ^ (e & 7)))*16) = kv;
    int d = idx >> 5, ce = idx & 31;
    uint4 vv = *(const uint4*)(vbase + d*256 + ce*8);
    *(uint4*)(vt_lds + d*512 + ((ce ^ (d & 7)))*16) = vv;
  }
  __syncthreads();
  const int lane = tid & 63, wid = tid >> 6;
  const int g = lane >> 4, lo = lane & 15;
  char* pw = p_lds + wid*4096;
  const float scale = 0.08838834764831845f;   // 128^-0.5
  const f32x4 vzero = {0.f, 0.f, 0.f, 0.f};

  for (int mt = 0; mt < 2; ++mt){
    const int crow = chalf + wid*32 + mt*16;
    const u16* qr = qb + ((size_t)bs*256 + crow + lo)*640 + (size_t)h*128;
    bf16x8 qf[4];
    #pragma unroll
    for (int kc = 0; kc < 4; ++kc) qf[kc] = *(const bf16x8*)(qr + kc*32 + g*8);

    f32x4 acc[16];
    #pragma unroll
    for (int et = 0; et < 16; ++et) acc[et] = vzero;
    #pragma unroll
    for (int et = 0; et < 16; ++et)
      #pragma unroll
      for (int kc = 0; kc < 4; ++kc){
        bf16x8 bk = *(const bf16x8*)(k_lds + k_off(et*16 + lo, kc*32 + g*8));
        acc[et] = __builtin_amdgcn_mfma_f32_16x16x32_bf16(qf[kc], bk, acc[et], 0, 0, 0);
      }

    // softmax over e (row = c: held as (g,r) rows, col spread over lo lanes x et)
    float mx[4] = {-3.0e38f, -3.0e38f, -3.0e38f, -3.0e38f};
    #pragma unroll
    for (int et = 0; et < 16; ++et)
      #pragma unroll
      for (int r = 0; r < 4; ++r){
        float t = acc[et][r] * scale;
        acc[et][r] = t;
        mx[r] = fmaxf(mx[r], t);
      }
    #pragma unroll
    for (int msk = 1; msk < 16; msk <<= 1)
      #pragma unroll
      for (int r = 0; r < 4; ++r) mx[r] = fmaxf(mx[r], __shfl_xor(mx[r], msk));
    float sm[4] = {0.f, 0.f, 0.f, 0.f};
    #pragma unroll
    for (int et = 0; et < 16; ++et)
      #pragma unroll
      for (int r = 0; r < 4; ++r){
        float ex = __expf(acc[et][r] - mx[r]);
        acc[et][r] = ex;
        sm[r] += ex;
      }
    #pragma unroll
    for (int msk = 1; msk < 16; msk <<= 1)
      #pragma unroll
      for (int r = 0; r < 4; ++r) sm[r] += __shfl_xor(sm[r], msk);
    float inv[4];
    #pragma unroll
    for (int r = 0; r < 4; ++r) inv[r] = 1.0f / sm[r];

    f32x4 oacc[8];
    #pragma unroll
    for (int dt = 0; dt < 8; ++dt) oacc[dt] = vzero;

    #pragma unroll
    for (int half = 0; half < 2; ++half){
      // write this half's P (bf16) into the per-wave tile
      #pragma unroll
      for (int et2 = 0; et2 < 8; ++et2){
        int et = half*8 + et2;
        #pragma unroll
        for (int r = 0; r < 4; ++r)
          *(u16*)(pw + p_off(g*4 + r, et2*16 + lo)) = f2bf(acc[et][r] * inv[r]);
      }
      asm volatile("s_waitcnt lgkmcnt(0)" ::: "memory");
      bf16x8 pf[4];
      #pragma unroll
      for (int kc = 0; kc < 4; ++kc) pf[kc] = *(const bf16x8*)(pw + p_off(lo, kc*32 + g*8));
      #pragma unroll
      for (int dt = 0; dt < 8; ++dt)
        #pragma unroll
        for (int kc = 0; kc < 4; ++kc){
          bf16x8 bv = *(const bf16x8*)(vt_lds + vt_off(dt*16 + lo, half*128 + kc*32 + g*8));
          oacc[dt] = __builtin_amdgcn_mfma_f32_16x16x32_bf16(pf[kc], bv, oacc[dt], 0, 0, 0);
        }
      asm volatile("s_waitcnt lgkmcnt(0)" ::: "memory");  // reads done before P reused
    }

    u16* orow = ob + ((size_t)bs*256 + crow)*640 + (size_t)h*128;
    #pragma unroll
    for (int dt = 0; dt < 8; ++dt)
      #pragma unroll
      for (int r = 0; r < 4; ++r)
        orow[(size_t)(g*4 + r)*640 + dt*16 + lo] = f2bf(oacc[dt][r]);
  }
}

// ------------------------------------------------------------------
extern "C" void kernel_launch(void* const* d_in, const int* in_sizes, int n_in,
                              void* d_out, int out_size, void* d_ws, size_t ws_size,
                              hipStream_t stream) {
  (void)in_sizes; (void)n_in; (void)out_size; (void)ws_size;
  char* ws = (char*)d_ws;
  const size_t SZ = (size_t)16384 * 640 * 2;     // 20,971,520 B
  u16* XB  = (u16*)(ws);
  u16* QB  = (u16*)(ws + SZ);
  u16* KB  = (u16*)(ws + 2*SZ);
  u16* VTB = (u16*)(ws + 3*SZ);
  u16* AT  = XB;                                  // x is dead after gemm_qkv
  u16* WQB = (u16*)(ws + 4*SZ);
  u16* WKB = WQB + 409600;
  u16* WVB = WKB + 409600;
  u16* WPB = WVB + 409600;
  u16* BPB = WPB + 409600;
  unsigned* FLAG = (unsigned*)(BPB + 640);

  k_detect<<<1, 64, 0, stream>>>((const u16*)d_in[0], FLAG);

  struct { const void* s; u16* d; int n; } cv[6] = {
    { d_in[0], XB,  10485760 },
    { d_in[1], WQB,   409600 },
    { d_in[2], WKB,   409600 },
    { d_in[3], WVB,   409600 },
    { d_in[4], WPB,   409600 },
    { d_in[5], BPB,      640 },
  };
  for (int i = 0; i < 6; ++i){
    int n4 = cv[i].n >> 2;
    k_convert<<<(n4 + 255) / 256, 256, 0, stream>>>(cv[i].s, cv[i].d, n4, FLAG);
  }

  gemm_qkv<<<dim3(128, 15), 256, 0, stream>>>(XB, WQB, WKB, WVB, QB, KB, VTB);
  attn_fwd<<<640, 256, 0, stream>>>(QB, KB, VTB, AT);
  gemm_out<<<dim3(128, 5), 256, 0, stream>>>(AT, WPB, BPB, d_out, FLAG);
}

// Round 2
// 169.503 us; speedup vs baseline: 1.0940x; 1.0940x over previous
//
#include <hip/hip_runtime.h>

// B=2, S=32, C=256, L=640, H=5, D=128
// rows M = B*S*C = 16384, L = 640 = H*D
//
// ws layout (bytes):
//   XB  @ 0          : x as bf16 [16384][640]   (20,971,520) -- reused as attn_out after attn
//   QB  @ 1*SZ       : q bf16 [16384][640] (col = h*128+d)
//   KB  @ 2*SZ       : k bf16 [16384][640]
//   VTB @ 3*SZ       : v transposed bf16 [320 bsh][128 d][256 e]
//   WQB/WKB/WVB/WPB/BPB @ 4*SZ : weights bf16 (contiguous)
//   FLAG             : u32 (1 = inputs are fp32, 0 = inputs are bf16)

typedef unsigned short u16;
typedef __bf16 bf16x8 __attribute__((ext_vector_type(8)));
typedef float f32x4 __attribute__((ext_vector_type(4)));

__device__ __forceinline__ u16 f2bf(float f){
  union { float f; unsigned u; } v; v.f = f;
  unsigned r = v.u + 0x7fffu + ((v.u >> 16) & 1u);
  return (u16)(r >> 16);
}
__device__ __forceinline__ float bf2f(u16 u){
  union { unsigned u; float f; } v; v.u = ((unsigned)u) << 16;
  return v.f;
}

// async global->LDS, 16B per lane; lds dest is wave-uniform base + lane*16 (HW)
__device__ __forceinline__ void gload16(const u16* g, char* l){
  __builtin_amdgcn_global_load_lds((const __attribute__((address_space(1))) void*)g,
                                   (__attribute__((address_space(3))) void*)l, 16, 0, 0);
}

// ---- swizzled LDS byte offsets for the ATTENTION kernel only ----
// k_lds: [256 e][128 d], row = 256B (16 chunks)
__device__ __forceinline__ int k_off (int e, int d){ return e*256 + (((d>>3) ^ (e&7)))*16 + (d&7)*2; }
// vt_lds: [128 d][256 e], row = 512B (32 chunks, xor low 3 bits)
__device__ __forceinline__ int vt_off(int d, int e){ return d*512 + (((e>>3) ^ (d&7)))*16 + (e&7)*2; }
// p tile (per wave): [16 c][128 e], row = 256B
__device__ __forceinline__ int p_off (int c, int el){ return c*256 + (((el>>3) ^ ((c>>2)&3)))*16 + (el&7)*2; }

// ------------------------------------------------------------------
// Fused dtype-detect + convert of all 6 inputs -> bf16 workspace.
// Each block re-derives the flag from x's first 4KB (wave 0: 64x16 samples;
// fp32 data -> ~44% of low-u16 "bf16 exponents" >= 143; real bf16 -> 0).
// word4 space: x [0,2621440) | wq,wk,wv,wp [..+409600) | bp [..+160)
__global__ __launch_bounds__(256) void k_convert_all(
    const void* __restrict__ xsrc, const void* __restrict__ s1, const void* __restrict__ s2,
    const void* __restrict__ s3, const void* __restrict__ s4, const void* __restrict__ s5,
    u16* __restrict__ xb, u16* __restrict__ wb, unsigned* __restrict__ flagOut){
  __shared__ unsigned sflag;
  const int tid = threadIdx.x;
  const u16* xs = (const u16*)xsrc;
  if (tid < 64){
    int cnt = 0;
    for (int i = tid; i < 1024; i += 64){
      unsigned e = (xs[2*i] >> 7) & 0xffu;
      cnt += (e >= 143u) ? 1 : 0;
    }
    #pragma unroll
    for (int m = 1; m < 64; m <<= 1) cnt += __shfl_xor(cnt, m);
    if (tid == 0) sflag = (cnt > 16) ? 1u : 0u;
  }
  __syncthreads();
  const unsigned flag = sflag;
  if (blockIdx.x == 0 && tid == 0) *flagOut = flag;

  #pragma unroll
  for (int it = 0; it < 4; ++it){
    size_t i = (size_t)blockIdx.x*1024 + it*256 + tid;
    if (i >= 3031200) break;
    const void* src; size_t off; u16* dp;
    if (i < 2621440){
      src = xsrc; off = i; dp = xb + i*4;
    } else {
      size_t j = i - 2621440;
      if (j < 409600){
        int seg = (int)(j / 102400);
        off = j - (size_t)seg*102400;
        src = (seg==0) ? s1 : (seg==1) ? s2 : (seg==2) ? s3 : s4;
        dp = wb + j*4;
      } else {
        off = j - 409600; src = s5; dp = wb + j*4;   // bp contiguous after wp
      }
    }
    if (flag){
      float4 v = ((const float4*)src)[off];
      ushort4 o;
      o.x = f2bf(v.x); o.y = f2bf(v.y); o.z = f2bf(v.z); o.w = f2bf(v.w);
      *(ushort4*)dp = o;
    } else {
      *(ushort4*)dp = ((const ushort4*)src)[off];
    }
  }
}

// ------------------------------------------------------------------
// 128x128 tile GEMM core, K=640, A[ld 640] row-major, B given as [N][K].
// m97 structure: global_load_lds width=16 into LINEAR LDS [128 rows][32 k]
// (64B rows), 2 barriers per K-step, 4 waves (2x2), 4x4 16x16x32 frags/wave.
__device__ __forceinline__ void gemm_core(const u16* __restrict__ Ag, const u16* __restrict__ Bg,
                                          char* a_lds, char* b_lds, f32x4 acc[4][4]){
  const int tid = threadIdx.x;
  const int lane = tid & 63, wid = tid >> 6;
  const int g = lane >> 4, lo = lane & 15;
  const int wm = wid >> 1, wn = wid & 1;
  const f32x4 vzero = {0.f, 0.f, 0.f, 0.f};
  #pragma unroll
  for (int mt = 0; mt < 4; ++mt)
    #pragma unroll
    for (int nt = 0; nt < 4; ++nt) acc[mt][nt] = vzero;

  // staging geometry: 1KB chunk = 64 lanes x 16B = 16 rows x (32k*2B).
  // chunk c covers rows c*16 + (lane>>2), k-slot lane&3. Wave w does chunks
  // {w, w+4} of A and of B.
  const int srow = lane >> 2;
  const size_t sgoff = (size_t)srow*640 + (size_t)(lane & 3)*8;

  for (int kt = 0; kt < 20; ++kt){
    const u16* Akt = Ag + kt*32;
    const u16* Bkt = Bg + kt*32;
    __syncthreads();                       // previous tile fully consumed
    #pragma unroll
    for (int cc = 0; cc < 2; ++cc){
      const int c = wid + cc*4;
      gload16(Akt + (size_t)c*16*640 + sgoff, a_lds + c*1024);
      gload16(Bkt + (size_t)c*16*640 + sgoff, b_lds + c*1024);
    }
    __syncthreads();                       // compiler emits vmcnt(0) before barrier
    bf16x8 af[4], bfr[4];
    #pragma unroll
    for (int mt = 0; mt < 4; ++mt)
      af[mt] = *(const bf16x8*)(a_lds + (wm*64 + mt*16 + lo)*64 + g*16);
    #pragma unroll
    for (int nt = 0; nt < 4; ++nt)
      bfr[nt] = *(const bf16x8*)(b_lds + (wn*64 + nt*16 + lo)*64 + g*16);
    #pragma unroll
    for (int mt = 0; mt < 4; ++mt)
      #pragma unroll
      for (int nt = 0; nt < 4; ++nt)
        acc[mt][nt] = __builtin_amdgcn_mfma_f32_16x16x32_bf16(af[mt], bfr[nt], acc[mt][nt], 0, 0, 0);
  }
}

// QKV projection: grid (128 mtiles, 15), by -> proj p = by/5, head h = by%5.
// v is written TRANSPOSED per (bs,h): vtb[bsh][d][e].
__global__ __launch_bounds__(256, 2) void gemm_qkv(const u16* __restrict__ xb,
    const u16* __restrict__ wq, const u16* __restrict__ wk, const u16* __restrict__ wv,
    u16* __restrict__ qb, u16* __restrict__ kb, u16* __restrict__ vtb){
  __shared__ char smem[16384];
  const int m0 = blockIdx.x * 128;
  const int by = blockIdx.y;
  const int p = by / 5, h = by % 5;
  const u16* W = (p == 0) ? wq : (p == 1) ? wk : wv;
  f32x4 acc[4][4];
  gemm_core(xb + (size_t)m0*640, W + (size_t)h*128*640, smem, smem + 8192, acc);
  const int tid = threadIdx.x, lane = tid & 63, wid = tid >> 6;
  const int g = lane >> 4, lo = lane & 15;
  const int wm = wid >> 1, wn = wid & 1;
  #pragma unroll
  for (int mt = 0; mt < 4; ++mt)
    #pragma unroll
    for (int nt = 0; nt < 4; ++nt)
      #pragma unroll
      for (int r = 0; r < 4; ++r){
        int m  = m0 + wm*64 + mt*16 + g*4 + r;       // global row (b,s,c)
        int nn = wn*64 + nt*16 + lo;                 // d within head, 0..127
        u16 val = f2bf(acc[mt][nt][r]);
        if (p == 0)      qb[(size_t)m*640 + h*128 + nn] = val;
        else if (p == 1) kb[(size_t)m*640 + h*128 + nn] = val;
        else             vtb[((size_t)(m >> 8)*5 + h)*32768 + (size_t)nn*256 + (m & 255)] = val;
      }
}

// Output projection + bias; writes d_out as f32 or bf16 per detected flag.
__global__ __launch_bounds__(256, 2) void gemm_out(const u16* __restrict__ at,
    const u16* __restrict__ wpw, const u16* __restrict__ bpw,
    void* __restrict__ out, const unsigned* __restrict__ flag){
  __shared__ char smem[16384];
  const int m0 = blockIdx.x * 128;
  const int n0 = blockIdx.y * 128;
  f32x4 acc[4][4];
  gemm_core(at + (size_t)m0*640, wpw + (size_t)n0*640, smem, smem + 8192, acc);
  const int tid = threadIdx.x, lane = tid & 63, wid = tid >> 6;
  const int g = lane >> 4, lo = lane & 15;
  const int wm = wid >> 1, wn = wid & 1;
  const bool f32out = (*flag != 0u);
  #pragma unroll
  for (int mt = 0; mt < 4; ++mt)
    #pragma unroll
    for (int nt = 0; nt < 4; ++nt){
      int col = n0 + wn*64 + nt*16 + lo;
      float bv = bf2f(bpw[col]);
      #pragma unroll
      for (int r = 0; r < 4; ++r){
        int m = m0 + wm*64 + mt*16 + g*4 + r;
        float v = acc[mt][nt][r] + bv;
        if (f32out) ((float*)out)[(size_t)m*640 + col] = v;
        else        ((u16*)out)[(size_t)m*640 + col]   = f2bf(v);
      }
    }
}

// ------------------------------------------------------------------
// Attention: grid = 320 (b,s,h) x 2 c-halves = 640 blocks, 256 threads.
__global__ __launch_bounds__(256, 1) void attn_fwd(const u16* __restrict__ qb,
    const u16* __restrict__ kb, const u16* __restrict__ vtb, u16* __restrict__ ob){
  __shared__ char smem[147456];
  char* k_lds  = smem;               // 64 KiB
  char* vt_lds = smem + 65536;       // 64 KiB
  char* p_lds  = smem + 131072;      // 16 KiB = 4 waves x [16 c][128 e]
  const int tid = threadIdx.x;
  const int bsh = blockIdx.x >> 1;
  const int chalf = (blockIdx.x & 1) * 128;
  const int bs = bsh / 5, h = bsh % 5;
  const u16* kbase = kb + (size_t)bs*256*640 + (size_t)h*128;
  const u16* vbase = vtb + (size_t)bsh*32768;
  #pragma unroll 4
  for (int i = 0; i < 16; ++i){
    int idx = i*256 + tid;
    int e = idx >> 4, cd = idx & 15;
    uint4 kv = *(const uint4*)(kbase + (size_t)e*640 + cd*8);
    *(uint4*)(k_lds + e*256 + ((cd ^ (e & 7)))*16) = kv;
    int d = idx >> 5, ce = idx & 31;
    uint4 vv = *(const uint4*)(vbase + d*256 + ce*8);
    *(uint4*)(vt_lds + d*512 + ((ce ^ (d & 7)))*16) = vv;
  }
  __syncthreads();
  const int lane = tid & 63, wid = tid >> 6;
  const int g = lane >> 4, lo = lane & 15;
  char* pw = p_lds + wid*4096;
  const float scale = 0.08838834764831845f;   // 128^-0.5
  const f32x4 vzero = {0.f, 0.f, 0.f, 0.f};

  for (int mt = 0; mt < 2; ++mt){
    const int crow = chalf + wid*32 + mt*16;
    const u16* qr = qb + ((size_t)bs*256 + crow + lo)*640 + (size_t)h*128;
    bf16x8 qf[4];
    #pragma unroll
    for (int kc = 0; kc < 4; ++kc) qf[kc] = *(const bf16x8*)(qr + kc*32 + g*8);

    f32x4 acc[16];
    #pragma unroll
    for (int et = 0; et < 16; ++et) acc[et] = vzero;
    #pragma unroll
    for (int et = 0; et < 16; ++et)
      #pragma unroll
      for (int kc = 0; kc < 4; ++kc){
        bf16x8 bk = *(const bf16x8*)(k_lds + k_off(et*16 + lo, kc*32 + g*8));
        acc[et] = __builtin_amdgcn_mfma_f32_16x16x32_bf16(qf[kc], bk, acc[et], 0, 0, 0);
      }

    float mx[4] = {-3.0e38f, -3.0e38f, -3.0e38f, -3.0e38f};
    #pragma unroll
    for (int et = 0; et < 16; ++et)
      #pragma unroll
      for (int r = 0; r < 4; ++r){
        float t = acc[et][r] * scale;
        acc[et][r] = t;
        mx[r] = fmaxf(mx[r], t);
      }
    #pragma unroll
    for (int msk = 1; msk < 16; msk <<= 1)
      #pragma unroll
      for (int r = 0; r < 4; ++r) mx[r] = fmaxf(mx[r], __shfl_xor(mx[r], msk));
    float sm[4] = {0.f, 0.f, 0.f, 0.f};
    #pragma unroll
    for (int et = 0; et < 16; ++et)
      #pragma unroll
      for (int r = 0; r < 4; ++r){
        float ex = __expf(acc[et][r] - mx[r]);
        acc[et][r] = ex;
        sm[r] += ex;
      }
    #pragma unroll
    for (int msk = 1; msk < 16; msk <<= 1)
      #pragma unroll
      for (int r = 0; r < 4; ++r) sm[r] += __shfl_xor(sm[r], msk);
    float inv[4];
    #pragma unroll
    for (int r = 0; r < 4; ++r) inv[r] = 1.0f / sm[r];

    f32x4 oacc[8];
    #pragma unroll
    for (int dt = 0; dt < 8; ++dt) oacc[dt] = vzero;

    #pragma unroll
    for (int half = 0; half < 2; ++half){
      #pragma unroll
      for (int et2 = 0; et2 < 8; ++et2){
        int et = half*8 + et2;
        #pragma unroll
        for (int r = 0; r < 4; ++r)
          *(u16*)(pw + p_off(g*4 + r, et2*16 + lo)) = f2bf(acc[et][r] * inv[r]);
      }
      asm volatile("s_waitcnt lgkmcnt(0)" ::: "memory");
      bf16x8 pf[4];
      #pragma unroll
      for (int kc = 0; kc < 4; ++kc) pf[kc] = *(const bf16x8*)(pw + p_off(lo, kc*32 + g*8));
      #pragma unroll
      for (int dt = 0; dt < 8; ++dt)
        #pragma unroll
        for (int kc = 0; kc < 4; ++kc){
          bf16x8 bv = *(const bf16x8*)(vt_lds + vt_off(dt*16 + lo, half*128 + kc*32 + g*8));
          oacc[dt] = __builtin_amdgcn_mfma_f32_16x16x32_bf16(pf[kc], bv, oacc[dt], 0, 0, 0);
        }
      asm volatile("s_waitcnt lgkmcnt(0)" ::: "memory");
    }

    u16* orow = ob + ((size_t)bs*256 + crow)*640 + (size_t)h*128;
    #pragma unroll
    for (int dt = 0; dt < 8; ++dt)
      #pragma unroll
      for (int r = 0; r < 4; ++r)
        orow[(size_t)(g*4 + r)*640 + dt*16 + lo] = f2bf(oacc[dt][r]);
  }
}

// ------------------------------------------------------------------
extern "C" void kernel_launch(void* const* d_in, const int* in_sizes, int n_in,
                              void* d_out, int out_size, void* d_ws, size_t ws_size,
                              hipStream_t stream) {
  (void)in_sizes; (void)n_in; (void)out_size; (void)ws_size;
  char* ws = (char*)d_ws;
  const size_t SZ = (size_t)16384 * 640 * 2;     // 20,971,520 B
  u16* XB  = (u16*)(ws);
  u16* QB  = (u16*)(ws + SZ);
  u16* KB  = (u16*)(ws + 2*SZ);
  u16* VTB = (u16*)(ws + 3*SZ);
  u16* AT  = XB;                                  // x is dead after gemm_qkv
  u16* WQB = (u16*)(ws + 4*SZ);
  u16* WKB = WQB + 409600;
  u16* WVB = WKB + 409600;
  u16* WPB = WVB + 409600;
  u16* BPB = WPB + 409600;                        // contiguous after WPB
  unsigned* FLAG = (unsigned*)(BPB + 640);

  // fused detect+convert: 3,031,200 word4s, 1024/block -> 2961 blocks
  k_convert_all<<<2961, 256, 0, stream>>>(d_in[0], d_in[1], d_in[2], d_in[3],
                                          d_in[4], d_in[5], XB, WQB, FLAG);

  gemm_qkv<<<dim3(128, 15), 256, 0, stream>>>(XB, WQB, WKB, WVB, QB, KB, VTB);
  attn_fwd<<<640, 256, 0, stream>>>(QB, KB, VTB, AT);
  gemm_out<<<dim3(128, 5), 256, 0, stream>>>(AT, WPB, BPB, d_out, FLAG);
}

// Round 3
// 164.548 us; speedup vs baseline: 1.1269x; 1.0301x over previous
//
#include <hip/hip_runtime.h>

// B=2, S=32, C=256, L=640, H=5, D=128
// rows M = B*S*C = 16384, L = 640 = H*D
//
// ws layout (bytes):
//   XB  @ 0          : x as bf16 [16384][640]   (20,971,520) -- reused as attn_out after attn
//   QB  @ 1*SZ       : q bf16 [16384][640] (col = h*128+d)
//   KB  @ 2*SZ       : k bf16 [16384][640]
//   VTB @ 3*SZ       : v transposed bf16 [320 bsh][128 d][256 e]
//   WQB/WKB/WVB/WPB/BPB @ 4*SZ : weights bf16 (contiguous)
//   FLAG             : u32 (1 = inputs are fp32, 0 = inputs are bf16)

typedef unsigned short u16;
typedef __bf16 bf16x8 __attribute__((ext_vector_type(8)));
typedef float f32x4 __attribute__((ext_vector_type(4)));

__device__ __forceinline__ u16 f2bf(float f){
  union { float f; unsigned u; } v; v.f = f;
  unsigned r = v.u + 0x7fffu + ((v.u >> 16) & 1u);
  return (u16)(r >> 16);
}
__device__ __forceinline__ float bf2f(u16 u){
  union { unsigned u; float f; } v; v.u = ((unsigned)u) << 16;
  return v.f;
}

// async global->LDS, 16B per lane; lds dest is wave-uniform base + lane*16 (HW)
__device__ __forceinline__ void gload16(const u16* g, char* l){
  __builtin_amdgcn_global_load_lds((const __attribute__((address_space(1))) void*)g,
                                   (__attribute__((address_space(3))) void*)l, 16, 0, 0);
}

// ---- swizzled LDS byte offsets for the ATTENTION kernel only ----
__device__ __forceinline__ int k_off (int e, int d){ return e*256 + (((d>>3) ^ (e&7)))*16 + (d&7)*2; }
__device__ __forceinline__ int vt_off(int d, int e){ return d*512 + (((e>>3) ^ (d&7)))*16 + (e&7)*2; }
__device__ __forceinline__ int p_off (int c, int el){ return c*256 + (((el>>3) ^ ((c>>2)&3)))*16 + (el&7)*2; }

// ------------------------------------------------------------------
// Fused dtype-detect + convert of all 6 inputs -> bf16 workspace.
__global__ __launch_bounds__(256) void k_convert_all(
    const void* __restrict__ xsrc, const void* __restrict__ s1, const void* __restrict__ s2,
    const void* __restrict__ s3, const void* __restrict__ s4, const void* __restrict__ s5,
    u16* __restrict__ xb, u16* __restrict__ wb, unsigned* __restrict__ flagOut){
  __shared__ unsigned sflag;
  const int tid = threadIdx.x;
  const u16* xs = (const u16*)xsrc;
  if (tid < 64){
    int cnt = 0;
    for (int i = tid; i < 1024; i += 64){
      unsigned e = (xs[2*i] >> 7) & 0xffu;
      cnt += (e >= 143u) ? 1 : 0;
    }
    #pragma unroll
    for (int m = 1; m < 64; m <<= 1) cnt += __shfl_xor(cnt, m);
    if (tid == 0) sflag = (cnt > 16) ? 1u : 0u;
  }
  __syncthreads();
  const unsigned flag = sflag;
  if (blockIdx.x == 0 && tid == 0) *flagOut = flag;

  #pragma unroll
  for (int it = 0; it < 4; ++it){
    size_t i = (size_t)blockIdx.x*1024 + it*256 + tid;
    if (i >= 3031200) break;
    const void* src; size_t off; u16* dp;
    if (i < 2621440){
      src = xsrc; off = i; dp = xb + i*4;
    } else {
      size_t j = i - 2621440;
      if (j < 409600){
        int seg = (int)(j / 102400);
        off = j - (size_t)seg*102400;
        src = (seg==0) ? s1 : (seg==1) ? s2 : (seg==2) ? s3 : s4;
        dp = wb + j*4;
      } else {
        off = j - 409600; src = s5; dp = wb + j*4;   // bp contiguous after wp
      }
    }
    if (flag){
      float4 v = ((const float4*)src)[off];
      ushort4 o;
      o.x = f2bf(v.x); o.y = f2bf(v.y); o.z = f2bf(v.z); o.w = f2bf(v.w);
      *(ushort4*)dp = o;
    } else {
      *(ushort4*)dp = ((const ushort4*)src)[off];
    }
  }
}

// ------------------------------------------------------------------
// 128x128 tile GEMM core, K=640, BK=64, double-buffered 2-phase schedule.
// LDS layout per buffer: A [128 r][64 k] then B [128 r][64 k], rows 128B =
// 8 slots of 16B. Data stored SWIZZLED: linear(r, s) holds true (r, s^(r&7));
// writer pre-swizzles the GLOBAL source k-offset (global_load_lds dest must
// stay linear), reader XORs the slot. 16 lanes (lo) reading one true slot
// hit all 8 slot positions -> 2-way bank alias = free.
// Schedule (T3 minimum-2-phase): stage(next) BEFORE compute(cur); one
// __syncthreads per K-step (its vmcnt(0) drain lands after ~32 MFMA).
__device__ __forceinline__ void gemm_core(const u16* __restrict__ Ag, const u16* __restrict__ Bg,
                                          char* lds, f32x4 acc[4][4]){
  const int tid = threadIdx.x;
  const int lane = tid & 63, wid = tid >> 6;
  const int g = lane >> 4, lo = lane & 15;
  const int wm = wid >> 1, wn = wid & 1;
  const f32x4 vzero = {0.f, 0.f, 0.f, 0.f};
  #pragma unroll
  for (int mt = 0; mt < 4; ++mt)
    #pragma unroll
    for (int nt = 0; nt < 4; ++nt) acc[mt][nt] = vzero;

  // staging: chunk = 1KB = 8 rows x 8 slots; lane l -> row l>>3, slot l&7,
  // source k-offset pre-swizzled: ((l&7) ^ (l>>3)) * 8 elements.
  const int srow = lane >> 3;
  const size_t soff = (size_t)srow*640 + (size_t)(((lane & 7) ^ srow) * 8);

  #define STAGE(buf, kt) do {                                            \
    const u16* Akt_ = Ag + (kt)*64;                                      \
    const u16* Bkt_ = Bg + (kt)*64;                                      \
    _Pragma("unroll")                                                    \
    for (int cc = 0; cc < 4; ++cc){                                      \
      int c_ = wid*4 + cc;                                               \
      gload16(Akt_ + (size_t)c_*8*640 + soff, (buf) + c_*1024);          \
      gload16(Bkt_ + (size_t)c_*8*640 + soff, (buf) + 16384 + c_*1024);  \
    }                                                                    \
  } while(0)

  #define COMPUTE(buf) do {                                              \
    bf16x8 af[4][2], bfr[4][2];                                          \
    _Pragma("unroll")                                                    \
    for (int mt = 0; mt < 4; ++mt){                                      \
      int rr = wm*64 + mt*16 + lo;                                       \
      _Pragma("unroll")                                                  \
      for (int ks = 0; ks < 2; ++ks)                                     \
        af[mt][ks] = *(const bf16x8*)((buf) + rr*128 + (((ks*4+g) ^ (lo&7))*16)); \
    }                                                                    \
    _Pragma("unroll")                                                    \
    for (int nt = 0; nt < 4; ++nt){                                      \
      int rr = wn*64 + nt*16 + lo;                                       \
      _Pragma("unroll")                                                  \
      for (int ks = 0; ks < 2; ++ks)                                     \
        bfr[nt][ks] = *(const bf16x8*)((buf) + 16384 + rr*128 + (((ks*4+g) ^ (lo&7))*16)); \
    }                                                                    \
    _Pragma("unroll")                                                    \
    for (int mt = 0; mt < 4; ++mt)                                       \
      _Pragma("unroll")                                                  \
      for (int nt = 0; nt < 4; ++nt)                                     \
        _Pragma("unroll")                                                \
        for (int ks = 0; ks < 2; ++ks)                                   \
          acc[mt][nt] = __builtin_amdgcn_mfma_f32_16x16x32_bf16(af[mt][ks], bfr[nt][ks], acc[mt][nt], 0, 0, 0); \
  } while(0)

  char* buf0 = lds;
  char* buf1 = lds + 32768;

  STAGE(buf0, 0);
  __syncthreads();
  #pragma unroll 1
  for (int kt2 = 0; kt2 < 5; ++kt2){
    int kt = kt2*2;
    STAGE(buf1, kt+1);          // issue next-tile loads first (latency hidden)
    COMPUTE(buf0);
    __syncthreads();            // drains vmcnt -> buf1 ready
    if (kt2 < 4) STAGE(buf0, kt+2);
    COMPUTE(buf1);
    __syncthreads();
  }
  #undef STAGE
  #undef COMPUTE
}

// QKV projection: grid (128 mtiles, 15), by -> proj p = by/5, head h = by%5.
// v is written TRANSPOSED per (bs,h): vtb[bsh][d][e].
__global__ __launch_bounds__(256, 2) void gemm_qkv(const u16* __restrict__ xb,
    const u16* __restrict__ wq, const u16* __restrict__ wk, const u16* __restrict__ wv,
    u16* __restrict__ qb, u16* __restrict__ kb, u16* __restrict__ vtb){
  __shared__ char smem[65536];
  const int m0 = blockIdx.x * 128;
  const int by = blockIdx.y;
  const int p = by / 5, h = by % 5;
  const u16* W = (p == 0) ? wq : (p == 1) ? wk : wv;
  f32x4 acc[4][4];
  gemm_core(xb + (size_t)m0*640, W + (size_t)h*128*640, smem, acc);
  const int tid = threadIdx.x, lane = tid & 63, wid = tid >> 6;
  const int g = lane >> 4, lo = lane & 15;
  const int wm = wid >> 1, wn = wid & 1;
  #pragma unroll
  for (int mt = 0; mt < 4; ++mt)
    #pragma unroll
    for (int nt = 0; nt < 4; ++nt)
      #pragma unroll
      for (int r = 0; r < 4; ++r){
        int m  = m0 + wm*64 + mt*16 + g*4 + r;       // global row (b,s,c)
        int nn = wn*64 + nt*16 + lo;                 // d within head, 0..127
        u16 val = f2bf(acc[mt][nt][r]);
        if (p == 0)      qb[(size_t)m*640 + h*128 + nn] = val;
        else if (p == 1) kb[(size_t)m*640 + h*128 + nn] = val;
        else             vtb[((size_t)(m >> 8)*5 + h)*32768 + (size_t)nn*256 + (m & 255)] = val;
      }
}

// Output projection + bias; writes d_out as f32 or bf16 per detected flag.
__global__ __launch_bounds__(256, 2) void gemm_out(const u16* __restrict__ at,
    const u16* __restrict__ wpw, const u16* __restrict__ bpw,
    void* __restrict__ out, const unsigned* __restrict__ flag){
  __shared__ char smem[65536];
  const int m0 = blockIdx.x * 128;
  const int n0 = blockIdx.y * 128;
  f32x4 acc[4][4];
  gemm_core(at + (size_t)m0*640, wpw + (size_t)n0*640, smem, acc);
  const int tid = threadIdx.x, lane = tid & 63, wid = tid >> 6;
  const int g = lane >> 4, lo = lane & 15;
  const int wm = wid >> 1, wn = wid & 1;
  const bool f32out = (*flag != 0u);
  #pragma unroll
  for (int mt = 0; mt < 4; ++mt)
    #pragma unroll
    for (int nt = 0; nt < 4; ++nt){
      int col = n0 + wn*64 + nt*16 + lo;
      float bv = bf2f(bpw[col]);
      #pragma unroll
      for (int r = 0; r < 4; ++r){
        int m = m0 + wm*64 + mt*16 + g*4 + r;
        float v = acc[mt][nt][r] + bv;
        if (f32out) ((float*)out)[(size_t)m*640 + col] = v;
        else        ((u16*)out)[(size_t)m*640 + col]   = f2bf(v);
      }
    }
}

// ------------------------------------------------------------------
// Attention: grid = 320 (b,s,h) x 2 c-halves = 640 blocks, 256 threads.
__global__ __launch_bounds__(256, 1) void attn_fwd(const u16* __restrict__ qb,
    const u16* __restrict__ kb, const u16* __restrict__ vtb, u16* __restrict__ ob){
  __shared__ char smem[147456];
  char* k_lds  = smem;               // 64 KiB
  char* vt_lds = smem + 65536;       // 64 KiB
  char* p_lds  = smem + 131072;      // 16 KiB = 4 waves x [16 c][128 e]
  const int tid = threadIdx.x;
  const int bsh = blockIdx.x >> 1;
  const int chalf = (blockIdx.x & 1) * 128;
  const int bs = bsh / 5, h = bsh % 5;
  const u16* kbase = kb + (size_t)bs*256*640 + (size_t)h*128;
  const u16* vbase = vtb + (size_t)bsh*32768;
  #pragma unroll 4
  for (int i = 0; i < 16; ++i){
    int idx = i*256 + tid;
    int e = idx >> 4, cd = idx & 15;
    uint4 kv = *(const uint4*)(kbase + (size_t)e*640 + cd*8);
    *(uint4*)(k_lds + e*256 + ((cd ^ (e & 7)))*16) = kv;
    int d = idx >> 5, ce = idx & 31;
    uint4 vv = *(const uint4*)(vbase + d*256 + ce*8);
    *(uint4*)(vt_lds + d*512 + ((ce ^ (d & 7)))*16) = vv;
  }
  __syncthreads();
  const int lane = tid & 63, wid = tid >> 6;
  const int g = lane >> 4, lo = lane & 15;
  char* pw = p_lds + wid*4096;
  const float scale = 0.08838834764831845f;   // 128^-0.5
  const f32x4 vzero = {0.f, 0.f, 0.f, 0.f};

  for (int mt = 0; mt < 2; ++mt){
    const int crow = chalf + wid*32 + mt*16;
    const u16* qr = qb + ((size_t)bs*256 + crow + lo)*640 + (size_t)h*128;
    bf16x8 qf[4];
    #pragma unroll
    for (int kc = 0; kc < 4; ++kc) qf[kc] = *(const bf16x8*)(qr + kc*32 + g*8);

    f32x4 acc[16];
    #pragma unroll
    for (int et = 0; et < 16; ++et) acc[et] = vzero;
    #pragma unroll
    for (int et = 0; et < 16; ++et)
      #pragma unroll
      for (int kc = 0; kc < 4; ++kc){
        bf16x8 bk = *(const bf16x8*)(k_lds + k_off(et*16 + lo, kc*32 + g*8));
        acc[et] = __builtin_amdgcn_mfma_f32_16x16x32_bf16(qf[kc], bk, acc[et], 0, 0, 0);
      }

    float mx[4] = {-3.0e38f, -3.0e38f, -3.0e38f, -3.0e38f};
    #pragma unroll
    for (int et = 0; et < 16; ++et)
      #pragma unroll
      for (int r = 0; r < 4; ++r){
        float t = acc[et][r] * scale;
        acc[et][r] = t;
        mx[r] = fmaxf(mx[r], t);
      }
    #pragma unroll
    for (int msk = 1; msk < 16; msk <<= 1)
      #pragma unroll
      for (int r = 0; r < 4; ++r) mx[r] = fmaxf(mx[r], __shfl_xor(mx[r], msk));
    float sm[4] = {0.f, 0.f, 0.f, 0.f};
    #pragma unroll
    for (int et = 0; et < 16; ++et)
      #pragma unroll
      for (int r = 0; r < 4; ++r){
        float ex = __expf(acc[et][r] - mx[r]);
        acc[et][r] = ex;
        sm[r] += ex;
      }
    #pragma unroll
    for (int msk = 1; msk < 16; msk <<= 1)
      #pragma unroll
      for (int r = 0; r < 4; ++r) sm[r] += __shfl_xor(sm[r], msk);
    float inv[4];
    #pragma unroll
    for (int r = 0; r < 4; ++r) inv[r] = 1.0f / sm[r];

    f32x4 oacc[8];
    #pragma unroll
    for (int dt = 0; dt < 8; ++dt) oacc[dt] = vzero;

    #pragma unroll
    for (int half = 0; half < 2; ++half){
      #pragma unroll
      for (int et2 = 0; et2 < 8; ++et2){
        int et = half*8 + et2;
        #pragma unroll
        for (int r = 0; r < 4; ++r)
          *(u16*)(pw + p_off(g*4 + r, et2*16 + lo)) = f2bf(acc[et][r] * inv[r]);
      }
      asm volatile("s_waitcnt lgkmcnt(0)" ::: "memory");
      bf16x8 pf[4];
      #pragma unroll
      for (int kc = 0; kc < 4; ++kc) pf[kc] = *(const bf16x8*)(pw + p_off(lo, kc*32 + g*8));
      #pragma unroll
      for (int dt = 0; dt < 8; ++dt)
        #pragma unroll
        for (int kc = 0; kc < 4; ++kc){
          bf16x8 bv = *(const bf16x8*)(vt_lds + vt_off(dt*16 + lo, half*128 + kc*32 + g*8));
          oacc[dt] = __builtin_amdgcn_mfma_f32_16x16x32_bf16(pf[kc], bv, oacc[dt], 0, 0, 0);
        }
      asm volatile("s_waitcnt lgkmcnt(0)" ::: "memory");
    }

    u16* orow = ob + ((size_t)bs*256 + crow)*640 + (size_t)h*128;
    #pragma unroll
    for (int dt = 0; dt < 8; ++dt)
      #pragma unroll
      for (int r = 0; r < 4; ++r)
        orow[(size_t)(g*4 + r)*640 + dt*16 + lo] = f2bf(oacc[dt][r]);
  }
}

// ------------------------------------------------------------------
extern "C" void kernel_launch(void* const* d_in, const int* in_sizes, int n_in,
                              void* d_out, int out_size, void* d_ws, size_t ws_size,
                              hipStream_t stream) {
  (void)in_sizes; (void)n_in; (void)out_size; (void)ws_size;
  char* ws = (char*)d_ws;
  const size_t SZ = (size_t)16384 * 640 * 2;     // 20,971,520 B
  u16* XB  = (u16*)(ws);
  u16* QB  = (u16*)(ws + SZ);
  u16* KB  = (u16*)(ws + 2*SZ);
  u16* VTB = (u16*)(ws + 3*SZ);
  u16* AT  = XB;                                  // x is dead after gemm_qkv
  u16* WQB = (u16*)(ws + 4*SZ);
  u16* WKB = WQB + 409600;
  u16* WVB = WKB + 409600;
  u16* WPB = WVB + 409600;
  u16* BPB = WPB + 409600;                        // contiguous after WPB
  unsigned* FLAG = (unsigned*)(BPB + 640);

  k_convert_all<<<2961, 256, 0, stream>>>(d_in[0], d_in[1], d_in[2], d_in[3],
                                          d_in[4], d_in[5], XB, WQB, FLAG);

  gemm_qkv<<<dim3(128, 15), 256, 0, stream>>>(XB, WQB, WKB, WVB, QB, KB, VTB);
  attn_fwd<<<640, 256, 0, stream>>>(QB, KB, VTB, AT);
  gemm_out<<<dim3(128, 5), 256, 0, stream>>>(AT, WPB, BPB, d_out, FLAG);
}